// Round 7
// baseline (573.223 us; speedup 1.0000x reference)
//
#include <hip/hip_runtime.h>
#include <stdint.h>

#define NPASS 9
#define NTHR  256
#define CPT   16                    // elements per thread, in registers
#define WIDTH (NTHR * CPT)          // 4096 elements per block-tile
#define HALO  20                    // garbage margin (needs >= 2*NPASS = 18; 20 keeps float4 alignment)
#define TOUT  (WIDTH - 2 * HALO)    // 4056 valid outputs per block

// ---- Threefry-2x32 (20 rounds), bit-exact vs JAX threefry2x32, constexpr-capable ----
struct TF2 { uint32_t a, b; };

__host__ __device__ constexpr uint32_t rotl32(uint32_t x, int d) {
  return (x << d) | (x >> (32 - d));
}

__host__ __device__ constexpr TF2 threefry2x32_c(uint32_t k0, uint32_t k1,
                                                 uint32_t x0, uint32_t x1) {
  uint32_t ks2 = k0 ^ k1 ^ 0x1BD11BDAu;
  x0 += k0; x1 += k1;
  x0 += x1; x1 = rotl32(x1, 13); x1 ^= x0;
  x0 += x1; x1 = rotl32(x1, 15); x1 ^= x0;
  x0 += x1; x1 = rotl32(x1, 26); x1 ^= x0;
  x0 += x1; x1 = rotl32(x1, 6);  x1 ^= x0;
  x0 += k1; x1 += ks2 + 1u;
  x0 += x1; x1 = rotl32(x1, 17); x1 ^= x0;
  x0 += x1; x1 = rotl32(x1, 29); x1 ^= x0;
  x0 += x1; x1 = rotl32(x1, 16); x1 ^= x0;
  x0 += x1; x1 = rotl32(x1, 24); x1 ^= x0;
  x0 += ks2; x1 += k0 + 2u;
  x0 += x1; x1 = rotl32(x1, 13); x1 ^= x0;
  x0 += x1; x1 = rotl32(x1, 15); x1 ^= x0;
  x0 += x1; x1 = rotl32(x1, 26); x1 ^= x0;
  x0 += x1; x1 = rotl32(x1, 6);  x1 ^= x0;
  x0 += k0; x1 += k1 + 3u;
  x0 += x1; x1 = rotl32(x1, 17); x1 ^= x0;
  x0 += x1; x1 = rotl32(x1, 29); x1 ^= x0;
  x0 += x1; x1 = rotl32(x1, 16); x1 ^= x0;
  x0 += x1; x1 = rotl32(x1, 24); x1 ^= x0;
  x0 += k1; x1 += ks2 + 4u;
  x0 += x1; x1 = rotl32(x1, 13); x1 ^= x0;
  x0 += x1; x1 = rotl32(x1, 15); x1 ^= x0;
  x0 += x1; x1 = rotl32(x1, 26); x1 ^= x0;
  x0 += x1; x1 = rotl32(x1, 6);  x1 ^= x0;
  x0 += ks2; x1 += k0 + 5u;
  return TF2{x0, x1};
}

// Per-pass expanded constants: C0 = x0-init, C1 = x1-key, C2..C11 = 5 key injections.
struct PassConsts { uint32_t c[12]; };

__host__ __device__ constexpr PassConsts make_pc(int k) {
  // fold_in(key(42), k) = threefry2x32((0,42), (0,k))
  TF2 kk = threefry2x32_c(0u, 42u, 0u, (uint32_t)k);
  uint32_t k0 = kk.a, k1 = kk.b;
  uint32_t ks2 = k0 ^ k1 ^ 0x1BD11BDAu;
  return PassConsts{{ k0, k1,
                      k1, ks2 + 1u,
                      ks2, k0 + 2u,
                      k0, k1 + 3u,
                      k1, ks2 + 4u,
                      ks2, k0 + 5u }};
}

constexpr PassConsts PC[NPASS] = {
  make_pc(0), make_pc(1), make_pc(2), make_pc(3), make_pc(4),
  make_pc(5), make_pc(6), make_pc(7), make_pc(8)
};

__device__ __forceinline__ uint32_t rotl_a(uint32_t x, int r) {
  return __builtin_amdgcn_alignbit(x, x, 32 - r);
}

// partitionable random_bits: bits[i] = o0 ^ o1 of threefry(key, (0, i));
// bernoulli(0.5): uniform < 0.5  <=>  MSB == 0  -> "rough". x1 arrives pre-keyed (c + C[1]).
__device__ __forceinline__ bool rough_hash(uint32_t x1, const uint32_t* C) {
  uint32_t x0 = C[0] + x1;                          // round 1 add, mov folded
  x1 = rotl_a(x1, 13); x1 ^= x0;
  x0 += x1; x1 = rotl_a(x1, 15); x1 ^= x0;
  x0 += x1; x1 = rotl_a(x1, 26); x1 ^= x0;
  x0 += x1; x1 = rotl_a(x1, 6);  x1 ^= x0;
  x1 += C[3]; x0 = x0 + C[2] + x1;
  x1 = rotl_a(x1, 17); x1 ^= x0;
  x0 += x1; x1 = rotl_a(x1, 29); x1 ^= x0;
  x0 += x1; x1 = rotl_a(x1, 16); x1 ^= x0;
  x0 += x1; x1 = rotl_a(x1, 24); x1 ^= x0;
  x1 += C[5]; x0 = x0 + C[4] + x1;
  x1 = rotl_a(x1, 13); x1 ^= x0;
  x0 += x1; x1 = rotl_a(x1, 15); x1 ^= x0;
  x0 += x1; x1 = rotl_a(x1, 26); x1 ^= x0;
  x0 += x1; x1 = rotl_a(x1, 6);  x1 ^= x0;
  x1 += C[7]; x0 = x0 + C[6] + x1;
  x1 = rotl_a(x1, 17); x1 ^= x0;
  x0 += x1; x1 = rotl_a(x1, 29); x1 ^= x0;
  x0 += x1; x1 = rotl_a(x1, 16); x1 ^= x0;
  x0 += x1; x1 = rotl_a(x1, 24); x1 ^= x0;
  x1 += C[9]; x0 = x0 + C[8] + x1;
  x1 = rotl_a(x1, 13); x1 ^= x0;
  x0 += x1; x1 = rotl_a(x1, 15); x1 ^= x0;
  x0 += x1; x1 = rotl_a(x1, 26); x1 ^= x0;
  x0 += x1; x1 = rotl_a(x1, 6);  x1 ^= x0;
  return (int)((x0 + C[10]) ^ (x1 + C[11])) >= 0;
}

// out = c + ni*(0.5*st + 0.5*(c-y)) reassociated to c + (0.5*ni)*(st + (c-y)).
// rough: ni=+0.05 -> k=+0.025 ; smooth: ni=-0.1 -> k=-0.05
__device__ __forceinline__ float upd_sel(float m2, float m1, float c, float p1, float p2,
                                         float yv, bool rough) {
  float st = m2 - 4.0f * m1 + 6.0f * c - 4.0f * p1 + p2;
  float tt = st + (c - yv);
  float k = rough ? 0.025f : -0.05f;
  return c + k * tt;
}

__global__ __launch_bounds__(NTHR, 6) void rs_fused(const float* __restrict__ y,
                                                    float* __restrict__ dst, int n) {
  __shared__ float hb2[2 * NTHR * 5];   // halo-exchange double buffer only (10240 B)
  const int bid = blockIdx.x, tid = threadIdx.x;
  const int S = bid * TOUT;
  const int E = min(S + TOUT, n);
  if (E <= S) return;

  const int gbase = S - HALO + tid * CPT;   // 16B-aligned when in-range
  const bool fast = (bid > 0) && (S - HALO + WIDTH <= n) && (E <= n - 2);

  float yv[CPT];
  if (fast) {
#pragma unroll
    for (int q = 0; q < CPT / 4; ++q) {
      const float4 t = *(const float4*)(y + gbase + 4 * q);
      yv[4 * q + 0] = t.x; yv[4 * q + 1] = t.y; yv[4 * q + 2] = t.z; yv[4 * q + 3] = t.w;
    }
  } else {
    // clamped scalar loads; OOB slots hold finite garbage in the margin
#pragma unroll
    for (int j = 0; j < CPT; ++j) {
      int g = gbase + j;
      g = g < 0 ? 0 : (g > n - 1 ? n - 1 : g);
      yv[j] = y[g];
    }
  }
  float v[CPT];
#pragma unroll
  for (int j = 0; j < CPT; ++j) v[j] = yv[j];

  const uint32_t cb = (uint32_t)(gbase - 2);     // mask counter base (g-2)

  // stride-5 LDS slots -> 2-way bank aliasing (free); addresses fixed across passes.
  // Clamped wl/wr at block edges read own slot -> finite garbage in the margin.
  const int wsl = tid * 5;
  const int wl  = (tid == 0 ? 0 : tid - 1) * 5;
  const int wr  = (tid == NTHR - 1 ? NTHR - 1 : tid + 1) * 5;

  if (fast) {
#pragma unroll 1
    for (int p = 0; p < NPASS; ++p) {
      const uint32_t* C = PC[p].c;
      const uint32_t x1b = cb + C[1];
      float* hb = hb2 + (p & 1) * (NTHR * 5);    // double-buffered: 1 sync per pass
      hb[wsl + 0] = v[0]; hb[wsl + 1] = v[1];
      hb[wsl + 2] = v[CPT - 2]; hb[wsl + 3] = v[CPT - 1];
      __syncthreads();

      float s[CPT + 4];
      s[0] = hb[wl + 2]; s[1] = hb[wl + 3];
#pragma unroll
      for (int j = 0; j < CPT; ++j) s[j + 2] = v[j];
      s[CPT + 2] = hb[wr + 0]; s[CPT + 3] = hb[wr + 1];

#pragma unroll
      for (int j = 0; j < CPT; ++j) {
        v[j] = upd_sel(s[j], s[j + 1], s[j + 2], s[j + 3], s[j + 4], yv[j],
                       rough_hash(x1b + (uint32_t)j, C));
      }
    }

    const int l0 = tid * CPT;
    if (l0 >= HALO && l0 + CPT <= HALO + TOUT) {
#pragma unroll
      for (int q = 0; q < CPT / 4; ++q) {
        *(float4*)(dst + gbase + 4 * q) =
            make_float4(v[4 * q + 0], v[4 * q + 1], v[4 * q + 2], v[4 * q + 3]);
      }
    } else {
#pragma unroll
      for (int j = 0; j < CPT; ++j) {
        const int l = l0 + j;
        if (l >= HALO && l < HALO + TOUT) dst[gbase + j] = v[j];
      }
    }
  } else {
    // edge blocks (first / tail): same register+exchange structure, but each
    // element applies the exact boundary formula every pass:
    //   g==0: copy; g==1: one-sided stencil; g>=n-2: reset to y; else interior.
    // Garbage margins / OOB slots never feed a valid output (trapezoid + boundary cut).
#pragma unroll 1
    for (int p = 0; p < NPASS; ++p) {
      const uint32_t* C = PC[p].c;
      const uint32_t x1b = cb + C[1];
      float* hb = hb2 + (p & 1) * (NTHR * 5);
      hb[wsl + 0] = v[0]; hb[wsl + 1] = v[1];
      hb[wsl + 2] = v[CPT - 2]; hb[wsl + 3] = v[CPT - 1];
      __syncthreads();

      float s[CPT + 4];
      s[0] = hb[wl + 2]; s[1] = hb[wl + 3];
#pragma unroll
      for (int j = 0; j < CPT; ++j) s[j + 2] = v[j];
      s[CPT + 2] = hb[wr + 0]; s[CPT + 3] = hb[wr + 1];

#pragma unroll
      for (int j = 0; j < CPT; ++j) {
        const int g = gbase + j;
        const float m1 = s[j + 1], c = s[j + 2], p1 = s[j + 3], p2 = s[j + 4];
        float o;
        if (g == 0) {
          o = c;
        } else if (g == 1) {
          const float st1 = -2.0f * m1 + 5.0f * c - 4.0f * p1 + p2;
          o = c + 0.1f * (0.5f * st1 + 0.5f * (c - yv[j]));
        } else if (g >= n - 2) {
          o = yv[j];
        } else {
          o = upd_sel(s[j], m1, c, p1, p2, yv[j],
                      rough_hash(x1b + (uint32_t)j, C));
        }
        v[j] = o;
      }
    }

    const int l0 = tid * CPT;
#pragma unroll
    for (int j = 0; j < CPT; ++j) {
      const int l = l0 + j;
      const int g = gbase + j;
      if (l >= HALO && l < HALO + TOUT && g < n) dst[g] = v[j];
    }
  }
}

extern "C" void kernel_launch(void* const* d_in, const int* in_sizes, int n_in,
                              void* d_out, int out_size, void* d_ws, size_t ws_size,
                              hipStream_t stream) {
  const float* y = (const float*)d_in[0];
  float* out = (float*)d_out;
  const int n = in_sizes[0];
  const int blocks = (n + TOUT - 1) / TOUT;
  rs_fused<<<blocks, NTHR, 0, stream>>>(y, out, n);
}

// Round 8
// 561.479 us; speedup vs baseline: 1.0209x; 1.0209x over previous
//
#include <hip/hip_runtime.h>
#include <stdint.h>

#define NPASS 9
#define NTHR  256
#define CPT   8                     // elements per thread, in registers
#define WIDTH (NTHR * CPT)          // 2048 elements per block-tile
#define HALO  20                    // garbage margin (needs >= 2*NPASS = 18; 20 keeps float4 alignment)
#define TOUT  (WIDTH - 2 * HALO)    // 2008 valid outputs per block

// ---- Threefry-2x32 (20 rounds), bit-exact vs JAX threefry2x32, constexpr-capable ----
struct TF2 { uint32_t a, b; };

__host__ __device__ constexpr uint32_t rotl32(uint32_t x, int d) {
  return (x << d) | (x >> (32 - d));
}

__host__ __device__ constexpr TF2 threefry2x32_c(uint32_t k0, uint32_t k1,
                                                 uint32_t x0, uint32_t x1) {
  uint32_t ks2 = k0 ^ k1 ^ 0x1BD11BDAu;
  x0 += k0; x1 += k1;
  x0 += x1; x1 = rotl32(x1, 13); x1 ^= x0;
  x0 += x1; x1 = rotl32(x1, 15); x1 ^= x0;
  x0 += x1; x1 = rotl32(x1, 26); x1 ^= x0;
  x0 += x1; x1 = rotl32(x1, 6);  x1 ^= x0;
  x0 += k1; x1 += ks2 + 1u;
  x0 += x1; x1 = rotl32(x1, 17); x1 ^= x0;
  x0 += x1; x1 = rotl32(x1, 29); x1 ^= x0;
  x0 += x1; x1 = rotl32(x1, 16); x1 ^= x0;
  x0 += x1; x1 = rotl32(x1, 24); x1 ^= x0;
  x0 += ks2; x1 += k0 + 2u;
  x0 += x1; x1 = rotl32(x1, 13); x1 ^= x0;
  x0 += x1; x1 = rotl32(x1, 15); x1 ^= x0;
  x0 += x1; x1 = rotl32(x1, 26); x1 ^= x0;
  x0 += x1; x1 = rotl32(x1, 6);  x1 ^= x0;
  x0 += k0; x1 += k1 + 3u;
  x0 += x1; x1 = rotl32(x1, 17); x1 ^= x0;
  x0 += x1; x1 = rotl32(x1, 29); x1 ^= x0;
  x0 += x1; x1 = rotl32(x1, 16); x1 ^= x0;
  x0 += x1; x1 = rotl32(x1, 24); x1 ^= x0;
  x0 += k1; x1 += ks2 + 4u;
  x0 += x1; x1 = rotl32(x1, 13); x1 ^= x0;
  x0 += x1; x1 = rotl32(x1, 15); x1 ^= x0;
  x0 += x1; x1 = rotl32(x1, 26); x1 ^= x0;
  x0 += x1; x1 = rotl32(x1, 6);  x1 ^= x0;
  x0 += ks2; x1 += k0 + 5u;
  return TF2{x0, x1};
}

// Per-pass expanded constants: C0 = x0-init, C1 = x1-key, C2..C11 = 5 key injections.
struct PassConsts { uint32_t c[12]; };

__host__ __device__ constexpr PassConsts make_pc(int k) {
  // fold_in(key(42), k) = threefry2x32((0,42), (0,k))
  TF2 kk = threefry2x32_c(0u, 42u, 0u, (uint32_t)k);
  uint32_t k0 = kk.a, k1 = kk.b;
  uint32_t ks2 = k0 ^ k1 ^ 0x1BD11BDAu;
  return PassConsts{{ k0, k1,
                      k1, ks2 + 1u,
                      ks2, k0 + 2u,
                      k0, k1 + 3u,
                      k1, ks2 + 4u,
                      ks2, k0 + 5u }};
}

constexpr PassConsts PC[NPASS] = {
  make_pc(0), make_pc(1), make_pc(2), make_pc(3), make_pc(4),
  make_pc(5), make_pc(6), make_pc(7), make_pc(8)
};

__device__ __forceinline__ uint32_t rotl_a(uint32_t x, int r) {
  return __builtin_amdgcn_alignbit(x, x, 32 - r);
}

// partitionable random_bits: bits[i] = o0 ^ o1 of threefry(key, (0, i));
// bernoulli(0.5): uniform < 0.5  <=>  MSB == 0  -> "rough". x1 arrives pre-keyed (c + C[1]).
__device__ __forceinline__ bool rough_hash(uint32_t x1, const uint32_t* C) {
  uint32_t x0 = C[0] + x1;                          // round 1 add, mov folded
  x1 = rotl_a(x1, 13); x1 ^= x0;
  x0 += x1; x1 = rotl_a(x1, 15); x1 ^= x0;
  x0 += x1; x1 = rotl_a(x1, 26); x1 ^= x0;
  x0 += x1; x1 = rotl_a(x1, 6);  x1 ^= x0;
  x1 += C[3]; x0 = x0 + C[2] + x1;
  x1 = rotl_a(x1, 17); x1 ^= x0;
  x0 += x1; x1 = rotl_a(x1, 29); x1 ^= x0;
  x0 += x1; x1 = rotl_a(x1, 16); x1 ^= x0;
  x0 += x1; x1 = rotl_a(x1, 24); x1 ^= x0;
  x1 += C[5]; x0 = x0 + C[4] + x1;
  x1 = rotl_a(x1, 13); x1 ^= x0;
  x0 += x1; x1 = rotl_a(x1, 15); x1 ^= x0;
  x0 += x1; x1 = rotl_a(x1, 26); x1 ^= x0;
  x0 += x1; x1 = rotl_a(x1, 6);  x1 ^= x0;
  x1 += C[7]; x0 = x0 + C[6] + x1;
  x1 = rotl_a(x1, 17); x1 ^= x0;
  x0 += x1; x1 = rotl_a(x1, 29); x1 ^= x0;
  x0 += x1; x1 = rotl_a(x1, 16); x1 ^= x0;
  x0 += x1; x1 = rotl_a(x1, 24); x1 ^= x0;
  x1 += C[9]; x0 = x0 + C[8] + x1;
  x1 = rotl_a(x1, 13); x1 ^= x0;
  x0 += x1; x1 = rotl_a(x1, 15); x1 ^= x0;
  x0 += x1; x1 = rotl_a(x1, 26); x1 ^= x0;
  x0 += x1; x1 = rotl_a(x1, 6);  x1 ^= x0;
  return (int)((x0 + C[10]) ^ (x1 + C[11])) >= 0;
}

// out = c + ni*(0.5*st + 0.5*(c-y)) reassociated to c + (0.5*ni)*(st + (c-y)).
// rough: ni=+0.05 -> k=+0.025 ; smooth: ni=-0.1 -> k=-0.05
__device__ __forceinline__ float upd_sel(float m2, float m1, float c, float p1, float p2,
                                         float yv, bool rough) {
  float st = m2 - 4.0f * m1 + 6.0f * c - 4.0f * p1 + p2;
  float tt = st + (c - yv);
  float k = rough ? 0.025f : -0.05f;
  return c + k * tt;
}

__global__ __launch_bounds__(NTHR, 8) void rs_fused(const float* __restrict__ y,
                                                    float* __restrict__ dst, int n) {
  __shared__ float hb2[2 * NTHR * 5];   // halo-exchange double buffer only (10240 B)
  const int bid = blockIdx.x, tid = threadIdx.x;
  const int S = bid * TOUT;
  const int E = min(S + TOUT, n);
  if (E <= S) return;

  const int gbase = S - HALO + tid * CPT;   // 16B-aligned when in-range
  const bool fast = (bid > 0) && (S - HALO + WIDTH <= n) && (E <= n - 2);

  float y0, y1, y2, y3, y4, y5, y6, y7;
  if (fast) {
    const float4 ylo = *(const float4*)(y + gbase);
    const float4 yhi = *(const float4*)(y + gbase + 4);
    y0 = ylo.x; y1 = ylo.y; y2 = ylo.z; y3 = ylo.w;
    y4 = yhi.x; y5 = yhi.y; y6 = yhi.z; y7 = yhi.w;
  } else {
    // clamped scalar loads; OOB slots hold finite garbage in the margin
    float yy[CPT];
#pragma unroll
    for (int j = 0; j < CPT; ++j) {
      int g = gbase + j;
      g = g < 0 ? 0 : (g > n - 1 ? n - 1 : g);
      yy[j] = y[g];
    }
    y0 = yy[0]; y1 = yy[1]; y2 = yy[2]; y3 = yy[3];
    y4 = yy[4]; y5 = yy[5]; y6 = yy[6]; y7 = yy[7];
  }
  float v0 = y0, v1 = y1, v2 = y2, v3 = y3, v4 = y4, v5 = y5, v6 = y6, v7 = y7;

  const uint32_t cb = (uint32_t)(gbase - 2);     // mask counter base (g-2)

  // stride-5 LDS slots -> 2-way bank aliasing (free); addresses fixed across passes.
  // Clamped wl/wr at block edges read own slot -> finite garbage in the margin.
  const int wsl = tid * 5;
  const int wl  = (tid == 0 ? 0 : tid - 1) * 5;
  const int wr  = (tid == NTHR - 1 ? NTHR - 1 : tid + 1) * 5;

  if (fast) {
#pragma unroll 1
    for (int p = 0; p < NPASS; ++p) {
      const uint32_t* C = PC[p].c;
      const uint32_t x1b = cb + C[1];
      float* hb = hb2 + (p & 1) * (NTHR * 5);    // double-buffered: 1 sync per pass
      hb[wsl + 0] = v0; hb[wsl + 1] = v1; hb[wsl + 2] = v6; hb[wsl + 3] = v7;
      __syncthreads();
      const float lh0 = hb[wl + 2], lh1 = hb[wl + 3];
      const float rh0 = hb[wr + 0], rh1 = hb[wr + 1];

      const float n0 = upd_sel(lh0, lh1, v0, v1, v2, y0, rough_hash(x1b + 0u, C));
      const float n1 = upd_sel(lh1, v0, v1, v2, v3, y1, rough_hash(x1b + 1u, C));
      const float n2 = upd_sel(v0, v1, v2, v3, v4, y2, rough_hash(x1b + 2u, C));
      const float n3 = upd_sel(v1, v2, v3, v4, v5, y3, rough_hash(x1b + 3u, C));
      const float n4 = upd_sel(v2, v3, v4, v5, v6, y4, rough_hash(x1b + 4u, C));
      const float n5 = upd_sel(v3, v4, v5, v6, v7, y5, rough_hash(x1b + 5u, C));
      const float n6 = upd_sel(v4, v5, v6, v7, rh0, y6, rough_hash(x1b + 6u, C));
      const float n7 = upd_sel(v5, v6, v7, rh0, rh1, y7, rough_hash(x1b + 7u, C));
      v0 = n0; v1 = n1; v2 = n2; v3 = n3; v4 = n4; v5 = n5; v6 = n6; v7 = n7;
    }

    const int l0 = tid * CPT;
    if (l0 >= HALO && l0 + CPT <= HALO + TOUT) {
      *(float4*)(dst + gbase)     = make_float4(v0, v1, v2, v3);
      *(float4*)(dst + gbase + 4) = make_float4(v4, v5, v6, v7);
    } else {
      const float vv[CPT] = {v0, v1, v2, v3, v4, v5, v6, v7};
#pragma unroll
      for (int j = 0; j < CPT; ++j) {
        const int l = l0 + j;
        if (l >= HALO && l < HALO + TOUT) dst[gbase + j] = vv[j];
      }
    }
  } else {
    // edge blocks (first / tail): same register+exchange structure, but each
    // element applies the exact boundary formula every pass:
    //   g==0: copy; g==1: one-sided stencil; g>=n-2: reset to y; else interior.
    // Garbage margins / OOB slots never feed a valid output (trapezoid + boundary cut).
#pragma unroll 1
    for (int p = 0; p < NPASS; ++p) {
      const uint32_t* C = PC[p].c;
      const uint32_t x1b = cb + C[1];
      float* hb = hb2 + (p & 1) * (NTHR * 5);
      hb[wsl + 0] = v0; hb[wsl + 1] = v1; hb[wsl + 2] = v6; hb[wsl + 3] = v7;
      __syncthreads();
      const float lh0 = hb[wl + 2], lh1 = hb[wl + 3];
      const float rh0 = hb[wr + 0], rh1 = hb[wr + 1];

      const float m2a[CPT] = {lh0, lh1, v0, v1, v2, v3, v4, v5};
      const float m1a[CPT] = {lh1, v0, v1, v2, v3, v4, v5, v6};
      const float ca [CPT] = {v0, v1, v2, v3, v4, v5, v6, v7};
      const float p1a[CPT] = {v1, v2, v3, v4, v5, v6, v7, rh0};
      const float p2a[CPT] = {v2, v3, v4, v5, v6, v7, rh0, rh1};
      const float ya [CPT] = {y0, y1, y2, y3, y4, y5, y6, y7};
      float out[CPT];
#pragma unroll
      for (int j = 0; j < CPT; ++j) {
        const int g = gbase + j;
        const float c = ca[j], m1 = m1a[j], p1 = p1a[j], p2 = p2a[j], yv = ya[j];
        float o;
        if (g == 0) {
          o = c;
        } else if (g == 1) {
          const float st1 = -2.0f * m1 + 5.0f * c - 4.0f * p1 + p2;
          o = c + 0.1f * (0.5f * st1 + 0.5f * (c - yv));
        } else if (g >= n - 2) {
          o = yv;
        } else {
          o = upd_sel(m2a[j], m1, c, p1, p2, yv, rough_hash(x1b + (uint32_t)j, C));
        }
        out[j] = o;
      }
      v0 = out[0]; v1 = out[1]; v2 = out[2]; v3 = out[3];
      v4 = out[4]; v5 = out[5]; v6 = out[6]; v7 = out[7];
    }

    const float vv[CPT] = {v0, v1, v2, v3, v4, v5, v6, v7};
    const int l0 = tid * CPT;
#pragma unroll
    for (int j = 0; j < CPT; ++j) {
      const int l = l0 + j;
      const int g = gbase + j;
      if (l >= HALO && l < HALO + TOUT && g < n) dst[g] = vv[j];
    }
  }
}

extern "C" void kernel_launch(void* const* d_in, const int* in_sizes, int n_in,
                              void* d_out, int out_size, void* d_ws, size_t ws_size,
                              hipStream_t stream) {
  const float* y = (const float*)d_in[0];
  float* out = (float*)d_out;
  const int n = in_sizes[0];
  const int blocks = (n + TOUT - 1) / TOUT;
  rs_fused<<<blocks, NTHR, 0, stream>>>(y, out, n);
}